// Round 7
// baseline (943.434 us; speedup 1.0000x reference)
//
#include <hip/hip_runtime.h>

// Residual VQ: B=32, D=64, L=4096, NCB=4, K=512.
// out: z_q_aggregated [B][NCB][D][L] f32, then indices [B][L][NCB] (as f32).
//
// Bit-exact reproduction of the reference float32 pipeline (validated absmax=0):
//   dot[t][k]: mul-init + single-accumulator FMA chain, d ascending 0..63
//   sx, se:    numpy pairwise 8-accumulator sum of squares, exact bracketing
//   d2 = (sx - 2*dot) + se     (two f32 roundings; 2*dot exact)
//   argmin:    first minimum (lowest k)  [ascending-k scan, strict <]
//   cascade:   x_res -= e[idx]; z_q += e[idx] in plain f32
//
// v7: ONE TOKEN PER LANE. x[64] and zq[64] live in VGPRs; e and se are read
// at wave-uniform addresses (uniform k-loop index, const __restrict__ srcs)
// -> scalar s_load into SGPRs, consumed as the SGPR operand of v_fma. No LDS,
// no barriers, no shuffles, no cross-lane argmin (each lane owns its token).
// k-quartet ILP (4 independent 64-FMA chains). Grid 512 blocks x 256 thr =
// 2 blocks/CU = 8 waves/CU (grid-limited, same residency as v6 but barrier-
// free and LDS-pipe-free -> VALU-bound).

#define LL   4096
#define DD   64
#define KK   512
#define NCB  4
#define NTHR 256

#define ZQ_ELEMS (32LL * NCB * DD * LL)   // 33,554,432 floats

// numpy pairwise sum of squares, n=64, exact op order (8 accumulators)
__device__ __forceinline__ float np_pairwise_sq64(const float* p) {
#pragma clang fp contract(off)
    float r[8];
#pragma unroll
    for (int j = 0; j < 8; ++j) { float s = p[j] * p[j]; r[j] = s; }
#pragma unroll
    for (int i = 8; i < 64; i += 8)
#pragma unroll
        for (int j = 0; j < 8; ++j) { float s = p[i + j] * p[i + j]; r[j] = r[j] + s; }
    return ((r[0] + r[1]) + (r[2] + r[3])) + ((r[4] + r[5]) + (r[6] + r[7]));
}

// ---------------- Kernel A: se[c][k] = np.sum(e*e, -1) ----------------
__global__ void se_kernel(const float* __restrict__ cb, float* __restrict__ se) {
    int t = blockIdx.x * blockDim.x + threadIdx.x;
    if (t >= NCB * KK) return;
    se[t] = np_pairwise_sq64(cb + (size_t)t * DD);
}

// ---------------- Main kernel ----------------
__global__ __launch_bounds__(NTHR) void rvq_kernel(const float* __restrict__ x_in,
                                                   const float* __restrict__ cb,
                                                   const float* __restrict__ se,
                                                   float* __restrict__ out) {
    const int tid = threadIdx.x;
    const int tok = blockIdx.x * NTHR + tid;      // global token 0..131071
    const int b   = tok >> 12;                    // uniform within block
    const int l   = tok & 4095;

    // ---- load this lane's token column: x[d] = x_in[b][d][l] (coalesced) ----
    float x[DD];
    {
        const float* xb = x_in + (size_t)b * DD * LL + l;
#pragma unroll
        for (int d = 0; d < DD; ++d) x[d] = xb[(size_t)d * LL];
    }

    float zq[DD];
#pragma unroll
    for (int d = 0; d < DD; ++d) zq[d] = 0.f;

#pragma unroll 1
    for (int c = 0; c < NCB; ++c) {
        // ---- sx: numpy pairwise sum of squares, lane-local, exact order ----
        float sxv;
        {
#pragma clang fp contract(off)
            float r[8];
#pragma unroll
            for (int j = 0; j < 8; ++j) { float s = x[j] * x[j]; r[j] = s; }
#pragma unroll
            for (int i = 8; i < 64; i += 8)
#pragma unroll
                for (int j = 0; j < 8; ++j) { float s = x[i + j] * x[i + j]; r[j] = r[j] + s; }
            sxv = ((r[0] + r[1]) + (r[2] + r[3])) + ((r[4] + r[5]) + (r[6] + r[7]));
        }

        float bestv = __builtin_inff();
        int   besti = 0;

        // ---- k-scan, quartets of 4 independent mul-init+FMA chains.
        // k0, addresses are wave-uniform -> e/se load as s_load (SGPR),
        // consumed as the scalar operand of v_fma. ----
#pragma unroll 1
        for (int k0 = 0; k0 < KK; k0 += 4) {
#pragma clang fp contract(off)
            const float* ep = cb + ((size_t)(c * KK + k0)) * DD;
            float dot0 = x[0] * ep[0];
            float dot1 = x[0] * ep[DD];
            float dot2 = x[0] * ep[2 * DD];
            float dot3 = x[0] * ep[3 * DD];
#pragma unroll
            for (int d = 1; d < DD; ++d) {
                dot0 = fmaf(x[d], ep[d], dot0);
                dot1 = fmaf(x[d], ep[DD + d], dot1);
                dot2 = fmaf(x[d], ep[2 * DD + d], dot2);
                dot3 = fmaf(x[d], ep[3 * DD + d], dot3);
            }
            const float* sep = se + c * KK + k0;
            {
                const float twod = 2.0f * dot0;           // exact (x2)
                const float d2 = (sxv - twod) + sep[0];   // two f32 roundings
                if (d2 < bestv) { bestv = d2; besti = k0; }
            }
            {
                const float twod = 2.0f * dot1;
                const float d2 = (sxv - twod) + sep[1];
                if (d2 < bestv) { bestv = d2; besti = k0 + 1; }
            }
            {
                const float twod = 2.0f * dot2;
                const float d2 = (sxv - twod) + sep[2];
                if (d2 < bestv) { bestv = d2; besti = k0 + 2; }
            }
            {
                const float twod = 2.0f * dot3;
                const float d2 = (sxv - twod) + sep[3];
                if (d2 < bestv) { bestv = d2; besti = k0 + 3; }
            }
        }

        // ---- residual update + z_q accumulate (per-lane vector loads) ----
        {
#pragma clang fp contract(off)
            const float* er = cb + ((size_t)(c * KK) + besti) * DD;
#pragma unroll
            for (int d4 = 0; d4 < DD; d4 += 4) {
                const float4 ev = *reinterpret_cast<const float4*>(er + d4);
                x[d4 + 0] = x[d4 + 0] - ev.x;  zq[d4 + 0] = zq[d4 + 0] + ev.x;
                x[d4 + 1] = x[d4 + 1] - ev.y;  zq[d4 + 1] = zq[d4 + 1] + ev.y;
                x[d4 + 2] = x[d4 + 2] - ev.z;  zq[d4 + 2] = zq[d4 + 2] + ev.z;
                x[d4 + 3] = x[d4 + 3] - ev.w;  zq[d4 + 3] = zq[d4 + 3] + ev.w;
            }
        }

        // ---- store z_q slice (coalesced per-d dword stores) and index ----
        {
            float* zo = out + (((size_t)b * NCB + c) * DD) * LL + l;
#pragma unroll
            for (int d = 0; d < DD; ++d) zo[(size_t)d * LL] = zq[d];
            out[ZQ_ELEMS + ((size_t)b * LL + l) * NCB + c] = (float)besti;
        }
    }
}

extern "C" void kernel_launch(void* const* d_in, const int* in_sizes, int n_in,
                              void* d_out, int out_size, void* d_ws, size_t ws_size,
                              hipStream_t stream) {
    const float* x_in = (const float*)d_in[0];
    const float* cb   = (const float*)d_in[1];
    float* out = (float*)d_out;
    float* se  = (float*)d_ws;   // NCB*KK floats = 8 KB scratch

    se_kernel<<<dim3((NCB * KK + 255) / 256), dim3(256), 0, stream>>>(cb, se);
    rvq_kernel<<<dim3((32 * LL) / NTHR), dim3(NTHR), 0, stream>>>(x_in, cb, se, out);
}

// Round 8
// 941.715 us; speedup vs baseline: 1.0018x; 1.0018x over previous
//
#include <hip/hip_runtime.h>

// Residual VQ: B=32, D=64, L=4096, NCB=4, K=512.
// out: z_q_aggregated [B][NCB][D][L] f32, then indices [B][L][NCB] (as f32).
//
// Bit-exact reproduction of the reference float32 pipeline (validated absmax=0):
//   dot[t][k]: mul-init + single-accumulator FMA chain, d ascending 0..63
//   sx, se:    numpy pairwise 8-accumulator sum of squares, exact bracketing
//   d2 = (sx - 2*dot) + se     (two f32 roundings; 2*dot exact)
//   argmin:    first minimum (lowest k)  [ascending-k scan, strict <]
//   cascade:   x_res -= e[idx]; z_q += e[idx] in plain f32
//
// v8: v7 (one token per lane, zero LDS, zero barriers) with the e-read codegen
// fixed: v7's scalar ep[d] reads compiled to per-lane global_load_dword + 64b
// address arithmetic (~580 VALU insts/quartet vs 256 FMAs -> VALU time 2.3x
// the FMA floor, 499us busy vs 219us needed). Now e is read as float4 (64
// loads/quartet, constant imm offsets from one base) -> ~290 VALU/quartet.
// FMA chains, fold rounding order, argmin and cascade are op-identical.

#define LL   4096
#define DD   64
#define KK   512
#define NCB  4
#define NTHR 256

#define ZQ_ELEMS (32LL * NCB * DD * LL)   // 33,554,432 floats

// numpy pairwise sum of squares, n=64, exact op order (8 accumulators)
__device__ __forceinline__ float np_pairwise_sq64(const float* p) {
#pragma clang fp contract(off)
    float r[8];
#pragma unroll
    for (int j = 0; j < 8; ++j) { float s = p[j] * p[j]; r[j] = s; }
#pragma unroll
    for (int i = 8; i < 64; i += 8)
#pragma unroll
        for (int j = 0; j < 8; ++j) { float s = p[i + j] * p[i + j]; r[j] = r[j] + s; }
    return ((r[0] + r[1]) + (r[2] + r[3])) + ((r[4] + r[5]) + (r[6] + r[7]));
}

// ---------------- Kernel A: se[c][k] = np.sum(e*e, -1) ----------------
__global__ void se_kernel(const float* __restrict__ cb, float* __restrict__ se) {
    int t = blockIdx.x * blockDim.x + threadIdx.x;
    if (t >= NCB * KK) return;
    se[t] = np_pairwise_sq64(cb + (size_t)t * DD);
}

// ---------------- Main kernel ----------------
__global__ __launch_bounds__(NTHR) void rvq_kernel(const float* __restrict__ x_in,
                                                   const float* __restrict__ cb,
                                                   const float* __restrict__ se,
                                                   float* __restrict__ out) {
    const int tid = threadIdx.x;
    const int tok = blockIdx.x * NTHR + tid;      // global token 0..131071
    const int b   = tok >> 12;                    // uniform within block
    const int l   = tok & 4095;

    // ---- load this lane's token column: x[d] = x_in[b][d][l] (coalesced) ----
    float x[DD];
    {
        const float* xb = x_in + (size_t)b * DD * LL + l;
#pragma unroll
        for (int d = 0; d < DD; ++d) x[d] = xb[(size_t)d * LL];
    }

    float zq[DD];
#pragma unroll
    for (int d = 0; d < DD; ++d) zq[d] = 0.f;

#pragma unroll 1
    for (int c = 0; c < NCB; ++c) {
        // ---- sx: numpy pairwise sum of squares, lane-local, exact order ----
        float sxv;
        {
#pragma clang fp contract(off)
            float r[8];
#pragma unroll
            for (int j = 0; j < 8; ++j) { float s = x[j] * x[j]; r[j] = s; }
#pragma unroll
            for (int i = 8; i < 64; i += 8)
#pragma unroll
                for (int j = 0; j < 8; ++j) { float s = x[i + j] * x[i + j]; r[j] = r[j] + s; }
            sxv = ((r[0] + r[1]) + (r[2] + r[3])) + ((r[4] + r[5]) + (r[6] + r[7]));
        }

        float bestv = __builtin_inff();
        int   besti = 0;

        // ---- k-scan, quartets of 4 independent mul-init+FMA chains.
        // e read as float4 with constant offsets from one per-quartet base:
        // 64 loads/quartet, imm-offset folded (<=1020B fits 13-bit signed). ----
#pragma unroll 1
        for (int k0 = 0; k0 < KK; k0 += 4) {
            const float* ep = cb + ((size_t)(c * KK + k0)) * DD;
            float dot0, dot1, dot2, dot3;

#define EROW(J, D4) (*reinterpret_cast<const float4*>(ep + (J) * DD + 4 * (D4)))
#define CHAIN4(ACC, E, D4)                          \
            ACC = fmaf(x[4 * (D4) + 0], E.x, ACC);  \
            ACC = fmaf(x[4 * (D4) + 1], E.y, ACC);  \
            ACC = fmaf(x[4 * (D4) + 2], E.z, ACC);  \
            ACC = fmaf(x[4 * (D4) + 3], E.w, ACC);

            {   // d4 = 0: mul-init (== fmaf into +0) then 3 fmaf per chain
                const float4 e0 = EROW(0, 0);
                const float4 e1 = EROW(1, 0);
                const float4 e2 = EROW(2, 0);
                const float4 e3 = EROW(3, 0);
                dot0 = x[0] * e0.x;
                dot0 = fmaf(x[1], e0.y, dot0); dot0 = fmaf(x[2], e0.z, dot0); dot0 = fmaf(x[3], e0.w, dot0);
                dot1 = x[0] * e1.x;
                dot1 = fmaf(x[1], e1.y, dot1); dot1 = fmaf(x[2], e1.z, dot1); dot1 = fmaf(x[3], e1.w, dot1);
                dot2 = x[0] * e2.x;
                dot2 = fmaf(x[1], e2.y, dot2); dot2 = fmaf(x[2], e2.z, dot2); dot2 = fmaf(x[3], e2.w, dot2);
                dot3 = x[0] * e3.x;
                dot3 = fmaf(x[1], e3.y, dot3); dot3 = fmaf(x[2], e3.z, dot3); dot3 = fmaf(x[3], e3.w, dot3);
            }
#pragma unroll
            for (int d4 = 1; d4 < 16; ++d4) {
                const float4 e0 = EROW(0, d4);
                const float4 e1 = EROW(1, d4);
                const float4 e2 = EROW(2, d4);
                const float4 e3 = EROW(3, d4);
                CHAIN4(dot0, e0, d4)
                CHAIN4(dot1, e1, d4)
                CHAIN4(dot2, e2, d4)
                CHAIN4(dot3, e3, d4)
            }
#undef CHAIN4
#undef EROW

            // fold: d2 = (sx - 2*dot) + se, two f32 roundings (no contraction)
            {
#pragma clang fp contract(off)
                const float4 se4 = *reinterpret_cast<const float4*>(se + c * KK + k0);
                {
                    const float twod = 2.0f * dot0;           // exact (x2)
                    const float d2 = (sxv - twod) + se4.x;
                    if (d2 < bestv) { bestv = d2; besti = k0; }
                }
                {
                    const float twod = 2.0f * dot1;
                    const float d2 = (sxv - twod) + se4.y;
                    if (d2 < bestv) { bestv = d2; besti = k0 + 1; }
                }
                {
                    const float twod = 2.0f * dot2;
                    const float d2 = (sxv - twod) + se4.z;
                    if (d2 < bestv) { bestv = d2; besti = k0 + 2; }
                }
                {
                    const float twod = 2.0f * dot3;
                    const float d2 = (sxv - twod) + se4.w;
                    if (d2 < bestv) { bestv = d2; besti = k0 + 3; }
                }
            }
        }

        // ---- residual update + z_q accumulate (per-lane float4 gathers) ----
        {
#pragma clang fp contract(off)
            const float* er = cb + ((size_t)(c * KK) + besti) * DD;
#pragma unroll
            for (int d4 = 0; d4 < DD; d4 += 4) {
                const float4 ev = *reinterpret_cast<const float4*>(er + d4);
                x[d4 + 0] = x[d4 + 0] - ev.x;  zq[d4 + 0] = zq[d4 + 0] + ev.x;
                x[d4 + 1] = x[d4 + 1] - ev.y;  zq[d4 + 1] = zq[d4 + 1] + ev.y;
                x[d4 + 2] = x[d4 + 2] - ev.z;  zq[d4 + 2] = zq[d4 + 2] + ev.z;
                x[d4 + 3] = x[d4 + 3] - ev.w;  zq[d4 + 3] = zq[d4 + 3] + ev.w;
            }
        }

        // ---- store z_q slice (coalesced per-d dword stores) and index ----
        {
            float* zo = out + (((size_t)b * NCB + c) * DD) * LL + l;
#pragma unroll
            for (int d = 0; d < DD; ++d) zo[(size_t)d * LL] = zq[d];
            out[ZQ_ELEMS + ((size_t)b * LL + l) * NCB + c] = (float)besti;
        }
    }
}

extern "C" void kernel_launch(void* const* d_in, const int* in_sizes, int n_in,
                              void* d_out, int out_size, void* d_ws, size_t ws_size,
                              hipStream_t stream) {
    const float* x_in = (const float*)d_in[0];
    const float* cb   = (const float*)d_in[1];
    float* out = (float*)d_out;
    float* se  = (float*)d_ws;   // NCB*KK floats = 8 KB scratch

    se_kernel<<<dim3((NCB * KK + 255) / 256), dim3(256), 0, stream>>>(cb, se);
    rvq_kernel<<<dim3((32 * LL) / NTHR), dim3(NTHR), 0, stream>>>(x_in, cb, se, out);
}